// Round 1
// baseline (1658.329 us; speedup 1.0000x reference)
//
#include <hip/hip_runtime.h>
#include <math.h>

// Problem constants (B=1)
#define MM 1024   // mentions
#define DD 512    // emb dim
#define CC 128    // antecedent window
#define FFN 1024  // hidden
// sp_W0 row blocks: [0,512)=W_src, [512,1024)=W_ant, [1024,1536)=W_prod,
//                   [1536,1556)=W_spk, [1556,1576)=W_bkt

// ws layout (floats):
//  H[1024][3072]             @ 0          (cols 0..1023 ms-hidden pre-bias, 1024.. src_proj, 2048.. ant_proj)
//  slow_partial[1024][8][128] @ 3145728
//  spk_proj[2][1024]         @ 4194304
//  bkt_proj[10][1024]        @ 4196352
//  ms[1024]                  @ 4206592
//  loss_partial[1024]        @ 4207616

// ---------------- GEMM: H = emb @ [ms_W0 | W_src | W_ant]  (1024x512 * 512x3072)
__global__ __launch_bounds__(256) void gemm_h(
    const float* __restrict__ emb, const float* __restrict__ ms_W0,
    const float* __restrict__ sp_W0, float* __restrict__ H)
{
    const int n0 = blockIdx.x * 128;   // 0..2944
    const int m0 = blockIdx.y * 128;   // 0..896
    __shared__ float As[16][128];
    __shared__ float Bs[16][128];
    const int tid = threadIdx.x;
    const int tx = tid & 15, ty = tid >> 4;
    const int g = n0 >> 10;            // 0: ms_W0, 1: W_src, 2: W_ant
    const float* Bbase = (g == 0) ? ms_W0 : (sp_W0 + (size_t)(g - 1) * 512 * 1024);
    const int ncol = n0 & 1023;
    const int ar = tid >> 1, ak = (tid & 1) * 8;    // A loader: row,k-offset
    const float* Arow = emb + (size_t)(m0 + ar) * DD;
    const int kB = tid >> 4, fB = (tid & 15) * 8;   // B loader

    float acc[8][8];
#pragma unroll
    for (int i = 0; i < 8; ++i)
#pragma unroll
        for (int j = 0; j < 8; ++j) acc[i][j] = 0.f;

    for (int kt = 0; kt < DD; kt += 16) {
        float4 a0 = *(const float4*)(Arow + kt + ak);
        float4 a1 = *(const float4*)(Arow + kt + ak + 4);
        float4 b0 = *(const float4*)(Bbase + (size_t)(kt + kB) * 1024 + ncol + fB);
        float4 b1 = *(const float4*)(Bbase + (size_t)(kt + kB) * 1024 + ncol + fB + 4);
        __syncthreads();
        As[ak + 0][ar] = a0.x; As[ak + 1][ar] = a0.y; As[ak + 2][ar] = a0.z; As[ak + 3][ar] = a0.w;
        As[ak + 4][ar] = a1.x; As[ak + 5][ar] = a1.y; As[ak + 6][ar] = a1.z; As[ak + 7][ar] = a1.w;
        *(float4*)&Bs[kB][fB] = b0;
        *(float4*)&Bs[kB][fB + 4] = b1;
        __syncthreads();
#pragma unroll
        for (int kk = 0; kk < 16; ++kk) {
            float a[8], b[8];
            *(float4*)&a[0] = *(const float4*)&As[kk][ty * 8];
            *(float4*)&a[4] = *(const float4*)&As[kk][ty * 8 + 4];
            *(float4*)&b[0] = *(const float4*)&Bs[kk][tx * 8];
            *(float4*)&b[4] = *(const float4*)&Bs[kk][tx * 8 + 4];
#pragma unroll
            for (int i = 0; i < 8; ++i)
#pragma unroll
                for (int j = 0; j < 8; ++j)
                    acc[i][j] = fmaf(a[i], b[j], acc[i][j]);
        }
    }
#pragma unroll
    for (int i = 0; i < 8; ++i) {
        float* o = H + (size_t)(m0 + ty * 8 + i) * 3072 + n0 + tx * 8;
        *(float4*)o = *(float4*)&acc[i][0];
        *(float4*)(o + 4) = *(float4*)&acc[i][4];
    }
}

// ---------------- small projections: spk_proj[2][1024], bkt_proj[10][1024]
__global__ void small_proj(const float* __restrict__ speaker_emb,
                           const float* __restrict__ bucket_emb,
                           const float* __restrict__ sp_W0,
                           float* __restrict__ spk_proj, float* __restrict__ bkt_proj)
{
    int r = blockIdx.x; // 0..11
    const float* e; const float* W; float* out;
    if (r < 2) { e = speaker_emb + r * 20; W = sp_W0 + (size_t)1536 * 1024; out = spk_proj + r * 1024; }
    else       { e = bucket_emb + (r - 2) * 20; W = sp_W0 + (size_t)1556 * 1024; out = bkt_proj + (r - 2) * 1024; }
    float ek[20];
#pragma unroll
    for (int k = 0; k < 20; ++k) ek[k] = e[k];
    for (int f = threadIdx.x; f < 1024; f += blockDim.x) {
        float s = 0.f;
#pragma unroll
        for (int k = 0; k < 20; ++k) s = fmaf(ek[k], W[(size_t)k * 1024 + f], s);
        out[f] = s;
    }
}

// ---------------- mention scores: ms[m] = sum_f relu(H[m][f]+b0[f]) * W1[f] + b1
__global__ __launch_bounds__(256) void mention_score(
    const float* __restrict__ H, const float* __restrict__ ms_b0,
    const float* __restrict__ ms_W1, const float* __restrict__ ms_b1,
    float* __restrict__ ms)
{
    int m = blockIdx.x;
    float v = 0.f;
    for (int f = threadIdx.x; f < 1024; f += 256) {
        float h = H[(size_t)m * 3072 + f] + ms_b0[f];
        v += fmaxf(h, 0.f) * ms_W1[f];
    }
#pragma unroll
    for (int o = 1; o < 64; o <<= 1) v += __shfl_xor(v, o);
    __shared__ float sm[4];
    if ((threadIdx.x & 63) == 0) sm[threadIdx.x >> 6] = v;
    __syncthreads();
    if (threadIdx.x == 0) ms[m] = sm[0] + sm[1] + sm[2] + sm[3] + ms_b1[0];
}

// ---------------- the big one: per (m, f_chunk): prod GEMM + fused epilogue
__global__ __launch_bounds__(256) void pair_gemm(
    const float* __restrict__ emb, const float* __restrict__ sp_W0,
    const float* __restrict__ H, const float* __restrict__ spk_proj,
    const float* __restrict__ bkt_proj, const float* __restrict__ sp_b0,
    const float* __restrict__ sp_W1, const int* __restrict__ speaker,
    float* __restrict__ slow_partial)
{
    const int m = blockIdx.y;
    const int f0 = blockIdx.x * 128;
    __shared__ float Em[512];
    __shared__ float As[16][128];
    __shared__ float Bs[16][128];
    const int tid = threadIdx.x;
    const int tx = tid & 15, ty = tid >> 4;

    ((float2*)Em)[tid] = ((const float2*)(emb + (size_t)m * DD))[tid];
    __syncthreads();

    const int c_ld = tid >> 1, k_ld = (tid & 1) * 8;
    int a_ld = m - 1 - c_ld; if (a_ld < 0) a_ld = 0;
    const float* Arow = emb + (size_t)a_ld * DD;
    const int kB = tid >> 4, fB = (tid & 15) * 8;
    const float* Wp = sp_W0 + (size_t)1024 * 1024;  // W_prod rows

    float acc[8][8];
#pragma unroll
    for (int i = 0; i < 8; ++i)
#pragma unroll
        for (int j = 0; j < 8; ++j) acc[i][j] = 0.f;

    for (int kt = 0; kt < DD; kt += 16) {
        float4 a0 = *(const float4*)(Arow + kt + k_ld);
        float4 a1 = *(const float4*)(Arow + kt + k_ld + 4);
        a0.x *= Em[kt + k_ld + 0]; a0.y *= Em[kt + k_ld + 1];
        a0.z *= Em[kt + k_ld + 2]; a0.w *= Em[kt + k_ld + 3];
        a1.x *= Em[kt + k_ld + 4]; a1.y *= Em[kt + k_ld + 5];
        a1.z *= Em[kt + k_ld + 6]; a1.w *= Em[kt + k_ld + 7];
        float4 b0 = *(const float4*)(Wp + (size_t)(kt + kB) * 1024 + f0 + fB);
        float4 b1 = *(const float4*)(Wp + (size_t)(kt + kB) * 1024 + f0 + fB + 4);
        __syncthreads();
        As[k_ld + 0][c_ld] = a0.x; As[k_ld + 1][c_ld] = a0.y;
        As[k_ld + 2][c_ld] = a0.z; As[k_ld + 3][c_ld] = a0.w;
        As[k_ld + 4][c_ld] = a1.x; As[k_ld + 5][c_ld] = a1.y;
        As[k_ld + 6][c_ld] = a1.z; As[k_ld + 7][c_ld] = a1.w;
        *(float4*)&Bs[kB][fB] = b0;
        *(float4*)&Bs[kB][fB + 4] = b1;
        __syncthreads();
#pragma unroll
        for (int kk = 0; kk < 16; ++kk) {
            float a[8], b[8];
            *(float4*)&a[0] = *(const float4*)&As[kk][ty * 8];
            *(float4*)&a[4] = *(const float4*)&As[kk][ty * 8 + 4];
            *(float4*)&b[0] = *(const float4*)&Bs[kk][tx * 8];
            *(float4*)&b[4] = *(const float4*)&Bs[kk][tx * 8 + 4];
#pragma unroll
            for (int i = 0; i < 8; ++i)
#pragma unroll
                for (int j = 0; j < 8; ++j)
                    acc[i][j] = fmaf(a[i], b[j], acc[i][j]);
        }
    }

    // epilogue: pre = prod + src + ant + spk + bkt + b0; relu; * W1; reduce over f
    const float* srcp = H + (size_t)m * 3072 + 1024 + f0;
    const float* b0p = sp_b0 + f0;
    const float* w1p = sp_W1 + f0;
    const int spk_m = speaker[m];
#pragma unroll
    for (int i = 0; i < 8; ++i) {
        const int c = ty * 8 + i;
        int raw = m - 1 - c;
        int a = raw < 0 ? 0 : raw;
        const int ss = (speaker[a] == spk_m) ? 1 : 0;
        const int off = c + 1;
        int bkt;
        if (off <= 4) bkt = off;
        else { bkt = 31 - __clz(off) + 3; if (bkt > 9) bkt = 9; }
        const float* antp = H + (size_t)a * 3072 + 2048 + f0;
        const float* spkp = spk_proj + ss * 1024 + f0;
        const float* bktp = bkt_proj + bkt * 1024 + f0;
        float s = 0.f;
#pragma unroll
        for (int j = 0; j < 8; ++j) {
            const int f = tx * 8 + j;
            float pre = acc[i][j] + srcp[f] + antp[f] + spkp[f] + bktp[f] + b0p[f];
            s += fmaxf(pre, 0.f) * w1p[f];
        }
        s += __shfl_xor(s, 1); s += __shfl_xor(s, 2);
        s += __shfl_xor(s, 4); s += __shfl_xor(s, 8);
        if (tx == 0) slow_partial[(size_t)(m * 8 + blockIdx.x) * 128 + c] = s;
    }
}

// ---------------- softmax + per-mention loss
__device__ __forceinline__ float bsum2(float v, float* sm) {
#pragma unroll
    for (int o = 1; o < 64; o <<= 1) v += __shfl_xor(v, o);
    __syncthreads();
    if ((threadIdx.x & 63) == 0) sm[threadIdx.x >> 6] = v;
    __syncthreads();
    return sm[0] + sm[1];
}
__device__ __forceinline__ float bmax2(float v, float* sm) {
#pragma unroll
    for (int o = 1; o < 64; o <<= 1) v = fmaxf(v, __shfl_xor(v, o));
    __syncthreads();
    if ((threadIdx.x & 63) == 0) sm[threadIdx.x >> 6] = v;
    __syncthreads();
    return fmaxf(sm[0], sm[1]);
}

__global__ __launch_bounds__(128) void softmax_loss(
    const float* __restrict__ slow_partial, const float* __restrict__ ms,
    const float* __restrict__ sp_b1, const int* __restrict__ cluster,
    float* __restrict__ out, float* __restrict__ loss_partial)
{
    const int m = blockIdx.x, c = threadIdx.x;
    __shared__ float sm[2];
    float slow = 0.f;
#pragma unroll
    for (int fc = 0; fc < 8; ++fc) slow += slow_partial[(size_t)(m * 8 + fc) * 128 + c];
    const int raw = m - 1 - c;
    const bool maskv = raw >= 0;
    const int a = maskv ? raw : 0;
    float score = slow + sp_b1[0] + ms[m] + ms[a];
    if (!maskv) score = -INFINITY;

    float mx = fmaxf(bmax2(score, sm), 0.f);
    float e = expf(score - mx);
    float e0 = expf(0.f - mx);
    float sum = bsum2(e, sm) + e0;
    float p = e / sum, p0 = e0 / sum;
    const float eps = 1e-6f;
    p  = fminf(fmaxf(p,  eps), 1.f - eps);
    p0 = fminf(fmaxf(p0, eps), 1.f - eps);
    float sum2 = bsum2(p, sm) + p0;
    p /= sum2; p0 /= sum2;
    out[(size_t)m * 129 + 1 + c] = p;
    if (c == 0) out[(size_t)m * 129] = p0;

    const int cid = cluster[m];
    const bool lbl = maskv && (cid > 0) && (cluster[a] == cid);
    float anyc = bsum2(lbl ? 1.f : 0.f, sm);
    float lsum = bsum2(lbl ? -logf(p) : 0.f, sm);
    if (c == 0) {
        if (anyc == 0.f) lsum += -logf(p0);
        loss_partial[m] = lsum;
    }
}

__global__ void loss_sum(const float* __restrict__ lp, float* __restrict__ out) {
    float v = 0.f;
    for (int i = threadIdx.x; i < 1024; i += 256) v += lp[i];
#pragma unroll
    for (int o = 1; o < 64; o <<= 1) v += __shfl_xor(v, o);
    __shared__ float sm[4];
    if ((threadIdx.x & 63) == 0) sm[threadIdx.x >> 6] = v;
    __syncthreads();
    if (threadIdx.x == 0) out[(size_t)1024 * 129] = sm[0] + sm[1] + sm[2] + sm[3];
}

extern "C" void kernel_launch(void* const* d_in, const int* in_sizes, int n_in,
                              void* d_out, int out_size, void* d_ws, size_t ws_size,
                              hipStream_t stream)
{
    const float* emb   = (const float*)d_in[0];
    const int*   clus  = (const int*)  d_in[1];
    const int*   spk   = (const int*)  d_in[2];
    const float* ms_W0 = (const float*)d_in[3];
    const float* ms_b0 = (const float*)d_in[4];
    const float* ms_W1 = (const float*)d_in[5];
    const float* ms_b1 = (const float*)d_in[6];
    const float* sp_W0 = (const float*)d_in[7];
    const float* sp_b0 = (const float*)d_in[8];
    const float* sp_W1 = (const float*)d_in[9];
    const float* sp_b1 = (const float*)d_in[10];
    const float* spke  = (const float*)d_in[11];
    const float* bkte  = (const float*)d_in[12];

    float* ws = (float*)d_ws;
    float* H            = ws;
    float* slow_partial = ws + 3145728;
    float* spk_proj     = ws + 4194304;
    float* bkt_proj     = ws + 4196352;
    float* msc          = ws + 4206592;
    float* lossp        = ws + 4207616;
    float* out = (float*)d_out;

    hipLaunchKernelGGL(gemm_h, dim3(24, 8), dim3(256), 0, stream, emb, ms_W0, sp_W0, H);
    hipLaunchKernelGGL(small_proj, dim3(12), dim3(256), 0, stream, spke, bkte, sp_W0, spk_proj, bkt_proj);
    hipLaunchKernelGGL(mention_score, dim3(1024), dim3(256), 0, stream, H, ms_b0, ms_W1, ms_b1, msc);
    hipLaunchKernelGGL(pair_gemm, dim3(8, 1024), dim3(256), 0, stream,
                       emb, sp_W0, H, spk_proj, bkt_proj, sp_b0, sp_W1, spk, slow_partial);
    hipLaunchKernelGGL(softmax_loss, dim3(1024), dim3(128), 0, stream,
                       slow_partial, msc, sp_b1, clus, out, lossp);
    hipLaunchKernelGGL(loss_sum, dim3(1), dim3(256), 0, stream, lossp, out);
}

// Round 2
// 720.530 us; speedup vs baseline: 2.3015x; 2.3015x over previous
//
#include <hip/hip_runtime.h>
#include <math.h>

// Problem constants (B=1)
#define MM 1024   // mentions
#define DD 512    // emb dim
#define CC 128    // antecedent window
#define FFN 1024  // hidden
// sp_W0 row blocks: [0,512)=W_src, [512,1024)=W_ant, [1024,1536)=W_prod,
//                   [1536,1556)=W_spk, [1556,1576)=W_bkt

// ws layout (floats):
//  H[1024][3072]              @ 0        (cols 0..1023 ms-hidden, 1024.. src_proj, 2048.. ant_proj)
//  slow_partial[1024][8][128] @ 3145728
//  spk_proj[2][1024]          @ 4194304
//  bkt_proj[10][1024]         @ 4196352
//  ms[1024]                   @ 4206592
//  loss_partial[1024]         @ 4207616
//  embb bf16 [1024][512]      @ 4208640  (262144 floats)
//  Wt   bf16 [1024][512]      @ 4470784  (262144 floats)

typedef __attribute__((ext_vector_type(8))) short bf16x8;   // 8 bf16 = 4 VGPR
typedef __attribute__((ext_vector_type(4))) float f32x4;

__device__ __forceinline__ ushort bf16_rn(float x) {
    uint u = __float_as_uint(x);
    uint r = u + 0x7fffu + ((u >> 16) & 1u);
    return (ushort)(r >> 16);
}
__device__ __forceinline__ float bf16_to_f(ushort u) {
    return __uint_as_float(((uint)u) << 16);
}

// ---------------- prep: emb fp32 -> bf16
__global__ __launch_bounds__(256) void prep_emb(const float* __restrict__ emb,
                                                ushort* __restrict__ embb)
{
    int i = blockIdx.x * 256 + threadIdx.x;  // 262144 float2 pairs
    float2 v = ((const float2*)emb)[i];
    ushort2 o;
    o.x = bf16_rn(v.x);
    o.y = bf16_rn(v.y);
    ((ushort2*)embb)[i] = o;
}

// ---------------- prep: W_prod [k=512][f=1024] fp32 -> Wt [f][k] bf16
__global__ __launch_bounds__(256) void prep_wt(const float* __restrict__ sp_W0,
                                               ushort* __restrict__ Wt)
{
    __shared__ float t[64][65];
    const int k0 = blockIdx.x * 64;   // 8 tiles
    const int f0 = blockIdx.y * 64;   // 16 tiles
    const float* W = sp_W0 + (size_t)1024 * 1024;
    const int tr = threadIdx.x >> 6;      // 0..3
    const int tc = threadIdx.x & 63;
#pragma unroll
    for (int i = 0; i < 16; ++i) {
        int k = tr + i * 4;
        t[k][tc] = W[(size_t)(k0 + k) * 1024 + f0 + tc];
    }
    __syncthreads();
    const int f = threadIdx.x >> 2;       // 0..63
    const int c4 = threadIdx.x & 3;       // k chunk of 16
    ushort tmp[16];
#pragma unroll
    for (int j = 0; j < 16; ++j) tmp[j] = bf16_rn(t[c4 * 16 + j][f]);
    uint4* dst = (uint4*)(Wt + (size_t)(f0 + f) * 512 + k0 + c4 * 16);
    dst[0] = *(uint4*)&tmp[0];
    dst[1] = *(uint4*)&tmp[8];
}

// ---------------- GEMM: H = emb @ [ms_W0 | W_src | W_ant]  (1024x512 * 512x3072) fp32
__global__ __launch_bounds__(256) void gemm_h(
    const float* __restrict__ emb, const float* __restrict__ ms_W0,
    const float* __restrict__ sp_W0, float* __restrict__ H)
{
    const int n0 = blockIdx.x * 128;
    const int m0 = blockIdx.y * 128;
    __shared__ float As[16][128];
    __shared__ float Bs[16][128];
    const int tid = threadIdx.x;
    const int tx = tid & 15, ty = tid >> 4;
    const int g = n0 >> 10;
    const float* Bbase = (g == 0) ? ms_W0 : (sp_W0 + (size_t)(g - 1) * 512 * 1024);
    const int ncol = n0 & 1023;
    const int ar = tid >> 1, ak = (tid & 1) * 8;
    const float* Arow = emb + (size_t)(m0 + ar) * DD;
    const int kB = tid >> 4, fB = (tid & 15) * 8;

    float acc[8][8];
#pragma unroll
    for (int i = 0; i < 8; ++i)
#pragma unroll
        for (int j = 0; j < 8; ++j) acc[i][j] = 0.f;

    for (int kt = 0; kt < DD; kt += 16) {
        float4 a0 = *(const float4*)(Arow + kt + ak);
        float4 a1 = *(const float4*)(Arow + kt + ak + 4);
        float4 b0 = *(const float4*)(Bbase + (size_t)(kt + kB) * 1024 + ncol + fB);
        float4 b1 = *(const float4*)(Bbase + (size_t)(kt + kB) * 1024 + ncol + fB + 4);
        __syncthreads();
        As[ak + 0][ar] = a0.x; As[ak + 1][ar] = a0.y; As[ak + 2][ar] = a0.z; As[ak + 3][ar] = a0.w;
        As[ak + 4][ar] = a1.x; As[ak + 5][ar] = a1.y; As[ak + 6][ar] = a1.z; As[ak + 7][ar] = a1.w;
        *(float4*)&Bs[kB][fB] = b0;
        *(float4*)&Bs[kB][fB + 4] = b1;
        __syncthreads();
#pragma unroll
        for (int kk = 0; kk < 16; ++kk) {
            float a[8], b[8];
            *(float4*)&a[0] = *(const float4*)&As[kk][ty * 8];
            *(float4*)&a[4] = *(const float4*)&As[kk][ty * 8 + 4];
            *(float4*)&b[0] = *(const float4*)&Bs[kk][tx * 8];
            *(float4*)&b[4] = *(const float4*)&Bs[kk][tx * 8 + 4];
#pragma unroll
            for (int i = 0; i < 8; ++i)
#pragma unroll
                for (int j = 0; j < 8; ++j)
                    acc[i][j] = fmaf(a[i], b[j], acc[i][j]);
        }
    }
#pragma unroll
    for (int i = 0; i < 8; ++i) {
        float* o = H + (size_t)(m0 + ty * 8 + i) * 3072 + n0 + tx * 8;
        *(float4*)o = *(float4*)&acc[i][0];
        *(float4*)(o + 4) = *(float4*)&acc[i][4];
    }
}

// ---------------- small projections
__global__ void small_proj(const float* __restrict__ speaker_emb,
                           const float* __restrict__ bucket_emb,
                           const float* __restrict__ sp_W0,
                           float* __restrict__ spk_proj, float* __restrict__ bkt_proj)
{
    int r = blockIdx.x; // 0..11
    const float* e; const float* W; float* out;
    if (r < 2) { e = speaker_emb + r * 20; W = sp_W0 + (size_t)1536 * 1024; out = spk_proj + r * 1024; }
    else       { e = bucket_emb + (r - 2) * 20; W = sp_W0 + (size_t)1556 * 1024; out = bkt_proj + (r - 2) * 1024; }
    float ek[20];
#pragma unroll
    for (int k = 0; k < 20; ++k) ek[k] = e[k];
    for (int f = threadIdx.x; f < 1024; f += blockDim.x) {
        float s = 0.f;
#pragma unroll
        for (int k = 0; k < 20; ++k) s = fmaf(ek[k], W[(size_t)k * 1024 + f], s);
        out[f] = s;
    }
}

// ---------------- mention scores
__global__ __launch_bounds__(256) void mention_score(
    const float* __restrict__ H, const float* __restrict__ ms_b0,
    const float* __restrict__ ms_W1, const float* __restrict__ ms_b1,
    float* __restrict__ ms)
{
    int m = blockIdx.x;
    float v = 0.f;
    for (int f = threadIdx.x; f < 1024; f += 256) {
        float h = H[(size_t)m * 3072 + f] + ms_b0[f];
        v += fmaxf(h, 0.f) * ms_W1[f];
    }
#pragma unroll
    for (int o = 1; o < 64; o <<= 1) v += __shfl_xor(v, o);
    __shared__ float sm[4];
    if ((threadIdx.x & 63) == 0) sm[threadIdx.x >> 6] = v;
    __syncthreads();
    if (threadIdx.x == 0) ms[m] = sm[0] + sm[1] + sm[2] + sm[3] + ms_b1[0];
}

// ---------------- pair scorer: MFMA, registers-only GEMM, fused epilogue
// block = (m, f-tile of 128). 4 waves 2x2; wave = 64 c-rows x 64 f-cols (4x4 frags 16x16x32)
__global__ __launch_bounds__(256) void pair_mfma(
    const ushort* __restrict__ embb, const ushort* __restrict__ Wt,
    const float* __restrict__ H, const float* __restrict__ spk_proj,
    const float* __restrict__ bkt_proj, const float* __restrict__ sp_b0,
    const float* __restrict__ sp_W1, const int* __restrict__ speaker,
    float* __restrict__ slow_partial)
{
    const int m = blockIdx.y;
    const int f0 = blockIdx.x * 128;
    const int lane = threadIdx.x & 63;
    const int wave = threadIdx.x >> 6;
    const int wx = wave & 1, wy = wave >> 1;
    const int l15 = lane & 15, lq = lane >> 4;

    const ushort* em_row = embb + (size_t)m * 512;
    const ushort* arow[4];
#pragma unroll
    for (int mi = 0; mi < 4; ++mi) {
        int c = wy * 64 + mi * 16 + l15;      // A-operand row = lane&15
        int a = m - 1 - c; if (a < 0) a = 0;
        arow[mi] = embb + (size_t)a * 512;
    }
    const ushort* brow[4];
#pragma unroll
    for (int ni = 0; ni < 4; ++ni) {
        int f = f0 + wx * 64 + ni * 16 + l15; // B-operand col = lane&15
        brow[ni] = Wt + (size_t)f * 512;
    }

    f32x4 acc[4][4];
#pragma unroll
    for (int i = 0; i < 4; ++i)
#pragma unroll
        for (int j = 0; j < 4; ++j) acc[i][j] = (f32x4)0.f;

    for (int kt = 0; kt < 512; kt += 32) {
        const int ko = kt + lq * 8;           // lane's 8-k slice (16 B)
        bf16x8 emv = *(const bf16x8*)(em_row + ko);
        bf16x8 av[4], bv[4];
#pragma unroll
        for (int mi = 0; mi < 4; ++mi) av[mi] = *(const bf16x8*)(arow[mi] + ko);
#pragma unroll
        for (int ni = 0; ni < 4; ++ni) bv[ni] = *(const bf16x8*)(brow[ni] + ko);

        float emf[8];
#pragma unroll
        for (int j = 0; j < 8; ++j) emf[j] = bf16_to_f((ushort)emv[j]);

#pragma unroll
        for (int mi = 0; mi < 4; ++mi) {
            uint pr[4];
#pragma unroll
            for (int p = 0; p < 4; ++p) {
                float p0 = emf[2 * p]     * bf16_to_f((ushort)av[mi][2 * p]);
                float p1 = emf[2 * p + 1] * bf16_to_f((ushort)av[mi][2 * p + 1]);
                // pack high halves: out = [p1.hi16, p0.hi16] (truncation)
                pr[p] = __builtin_amdgcn_perm(__float_as_uint(p1), __float_as_uint(p0), 0x07060302u);
            }
            bf16x8 af = *(bf16x8*)pr;
#pragma unroll
            for (int ni = 0; ni < 4; ++ni)
                acc[mi][ni] = __builtin_amdgcn_mfma_f32_16x16x32_bf16(af, bv[ni], acc[mi][ni], 0, 0, 0);
        }
    }

    // epilogue: pre = prod + src + ant + spk + bkt + b0; relu; *W1; reduce over f
    __shared__ float red[2][128];
    const int spk_m = speaker[m];
    float srcv[4], b0v[4], w1v[4];
#pragma unroll
    for (int ni = 0; ni < 4; ++ni) {
        int fcol = f0 + wx * 64 + ni * 16 + l15;
        srcv[ni] = H[(size_t)m * 3072 + 1024 + fcol];
        b0v[ni] = sp_b0[fcol];
        w1v[ni] = sp_W1[fcol];
    }
#pragma unroll
    for (int mi = 0; mi < 4; ++mi) {
#pragma unroll
        for (int r = 0; r < 4; ++r) {
            const int c = wy * 64 + mi * 16 + lq * 4 + r;   // C/D row = (lane>>4)*4+reg
            int a = m - 1 - c; if (a < 0) a = 0;
            const int ss = (speaker[a] == spk_m) ? 1 : 0;
            const int off = c + 1;
            int bkt;
            if (off <= 4) bkt = off;
            else { bkt = 31 - __clz(off) + 3; if (bkt > 9) bkt = 9; }
            const float* antp = H + (size_t)a * 3072 + 2048;
            const float* spkp = spk_proj + ss * 1024;
            const float* bktp = bkt_proj + bkt * 1024;
            float s = 0.f;
#pragma unroll
            for (int ni = 0; ni < 4; ++ni) {
                int fcol = f0 + wx * 64 + ni * 16 + l15;
                float pre = acc[mi][ni][r] + srcv[ni] + antp[fcol] + spkp[fcol] + bktp[fcol] + b0v[ni];
                s += fmaxf(pre, 0.f) * w1v[ni];
            }
            s += __shfl_xor(s, 1); s += __shfl_xor(s, 2);
            s += __shfl_xor(s, 4); s += __shfl_xor(s, 8);
            if (l15 == 0) red[wx][c] = s;
        }
    }
    __syncthreads();
    if (threadIdx.x < 128)
        slow_partial[(size_t)(m * 8 + blockIdx.x) * 128 + threadIdx.x] =
            red[0][threadIdx.x] + red[1][threadIdx.x];
}

// ---------------- softmax + per-mention loss
__device__ __forceinline__ float bsum2(float v, float* sm) {
#pragma unroll
    for (int o = 1; o < 64; o <<= 1) v += __shfl_xor(v, o);
    __syncthreads();
    if ((threadIdx.x & 63) == 0) sm[threadIdx.x >> 6] = v;
    __syncthreads();
    return sm[0] + sm[1];
}
__device__ __forceinline__ float bmax2(float v, float* sm) {
#pragma unroll
    for (int o = 1; o < 64; o <<= 1) v = fmaxf(v, __shfl_xor(v, o));
    __syncthreads();
    if ((threadIdx.x & 63) == 0) sm[threadIdx.x >> 6] = v;
    __syncthreads();
    return fmaxf(sm[0], sm[1]);
}

__global__ __launch_bounds__(128) void softmax_loss(
    const float* __restrict__ slow_partial, const float* __restrict__ ms,
    const float* __restrict__ sp_b1, const int* __restrict__ cluster,
    float* __restrict__ out, float* __restrict__ loss_partial)
{
    const int m = blockIdx.x, c = threadIdx.x;
    __shared__ float sm[2];
    float slow = 0.f;
#pragma unroll
    for (int fc = 0; fc < 8; ++fc) slow += slow_partial[(size_t)(m * 8 + fc) * 128 + c];
    const int raw = m - 1 - c;
    const bool maskv = raw >= 0;
    const int a = maskv ? raw : 0;
    float score = slow + sp_b1[0] + ms[m] + ms[a];
    if (!maskv) score = -INFINITY;

    float mx = fmaxf(bmax2(score, sm), 0.f);
    float e = expf(score - mx);
    float e0 = expf(0.f - mx);
    float sum = bsum2(e, sm) + e0;
    float p = e / sum, p0 = e0 / sum;
    const float eps = 1e-6f;
    p  = fminf(fmaxf(p,  eps), 1.f - eps);
    p0 = fminf(fmaxf(p0, eps), 1.f - eps);
    float sum2 = bsum2(p, sm) + p0;
    p /= sum2; p0 /= sum2;
    out[(size_t)m * 129 + 1 + c] = p;
    if (c == 0) out[(size_t)m * 129] = p0;

    const int cid = cluster[m];
    const bool lbl = maskv && (cid > 0) && (cluster[a] == cid);
    float anyc = bsum2(lbl ? 1.f : 0.f, sm);
    float lsum = bsum2(lbl ? -logf(p) : 0.f, sm);
    if (c == 0) {
        if (anyc == 0.f) lsum += -logf(p0);
        loss_partial[m] = lsum;
    }
}

__global__ void loss_sum(const float* __restrict__ lp, float* __restrict__ out) {
    float v = 0.f;
    for (int i = threadIdx.x; i < 1024; i += 256) v += lp[i];
#pragma unroll
    for (int o = 1; o < 64; o <<= 1) v += __shfl_xor(v, o);
    __shared__ float sm[4];
    if ((threadIdx.x & 63) == 0) sm[threadIdx.x >> 6] = v;
    __syncthreads();
    if (threadIdx.x == 0) out[(size_t)1024 * 129] = sm[0] + sm[1] + sm[2] + sm[3];
}

extern "C" void kernel_launch(void* const* d_in, const int* in_sizes, int n_in,
                              void* d_out, int out_size, void* d_ws, size_t ws_size,
                              hipStream_t stream)
{
    const float* emb   = (const float*)d_in[0];
    const int*   clus  = (const int*)  d_in[1];
    const int*   spk   = (const int*)  d_in[2];
    const float* ms_W0 = (const float*)d_in[3];
    const float* ms_b0 = (const float*)d_in[4];
    const float* ms_W1 = (const float*)d_in[5];
    const float* ms_b1 = (const float*)d_in[6];
    const float* sp_W0 = (const float*)d_in[7];
    const float* sp_b0 = (const float*)d_in[8];
    const float* sp_W1 = (const float*)d_in[9];
    const float* sp_b1 = (const float*)d_in[10];
    const float* spke  = (const float*)d_in[11];
    const float* bkte  = (const float*)d_in[12];

    float* ws = (float*)d_ws;
    float* H            = ws;
    float* slow_partial = ws + 3145728;
    float* spk_proj     = ws + 4194304;
    float* bkt_proj     = ws + 4196352;
    float* msc          = ws + 4206592;
    float* lossp        = ws + 4207616;
    ushort* embb        = (ushort*)(ws + 4208640);
    ushort* Wt          = (ushort*)(ws + 4470784);
    float* out = (float*)d_out;

    hipLaunchKernelGGL(prep_emb, dim3(1024), dim3(256), 0, stream, emb, embb);
    hipLaunchKernelGGL(prep_wt, dim3(8, 16), dim3(256), 0, stream, sp_W0, Wt);
    hipLaunchKernelGGL(gemm_h, dim3(24, 8), dim3(256), 0, stream, emb, ms_W0, sp_W0, H);
    hipLaunchKernelGGL(small_proj, dim3(12), dim3(256), 0, stream, spke, bkte, sp_W0, spk_proj, bkt_proj);
    hipLaunchKernelGGL(mention_score, dim3(1024), dim3(256), 0, stream, H, ms_b0, ms_W1, ms_b1, msc);
    hipLaunchKernelGGL(pair_mfma, dim3(8, 1024), dim3(256), 0, stream,
                       embb, Wt, H, spk_proj, bkt_proj, sp_b0, sp_W1, spk, slow_partial);
    hipLaunchKernelGGL(softmax_loss, dim3(1024), dim3(128), 0, stream,
                       slow_partial, msc, sp_b1, clus, out, lossp);
    hipLaunchKernelGGL(loss_sum, dim3(1), dim3(256), 0, stream, lossp, out);
}

// Round 3
// 434.123 us; speedup vs baseline: 3.8200x; 1.6597x over previous
//
#include <hip/hip_runtime.h>
#include <math.h>

// Problem constants (B=1)
#define MM 1024
#define DD 512
#define CC 128
#define LDSR 520   // padded A row stride in ushorts (520*2B = 1040 = 65*16 -> 2-way-free banks)

// ws layout (floats):
//  H[1024][3072]      @ 0        (0..1023 ms-hidden, 1024.. src_proj, 2048.. ant_proj)
//  slow[1024][128]    @ 3145728
//  spk_proj[2][1024]  @ 3276800
//  bkt_proj[10][1024] @ 3278848
//  ms[1024]           @ 3289088
//  lossp[1024]        @ 3290112
//  embb bf16[1024][512]  @ 3291136 (262144 floats)
//  Wall bf16[4096][512]  @ 3553280 (1048576 floats)
//    Wall rows: [0,1024)=ms_W0^T, [1024,2048)=W_src^T, [2048,3072)=W_ant^T, [3072,4096)=W_prod^T

typedef __attribute__((ext_vector_type(8))) short bf16x8;
typedef __attribute__((ext_vector_type(4))) float f32x4;

__device__ __forceinline__ ushort bf16_rn(float x) {
    uint u = __float_as_uint(x);
    uint r = u + 0x7fffu + ((u >> 16) & 1u);
    return (ushort)(r >> 16);
}
__device__ __forceinline__ float bf16_to_f(ushort u) {
    return __uint_as_float(((uint)u) << 16);
}

// ---------------- prep: emb fp32 -> bf16
__global__ __launch_bounds__(256) void prep_emb(const float* __restrict__ emb,
                                                ushort* __restrict__ embb)
{
    int i = blockIdx.x * 256 + threadIdx.x;
    float2 v = ((const float2*)emb)[i];
    ushort2 o;
    o.x = bf16_rn(v.x);
    o.y = bf16_rn(v.y);
    ((ushort2*)embb)[i] = o;
}

// ---------------- prep: transpose+convert all W0 blocks -> Wall[4096 n][512 k] bf16
__global__ __launch_bounds__(256) void prep_wall(const float* __restrict__ ms_W0,
                                                 const float* __restrict__ sp_W0,
                                                 ushort* __restrict__ Wall)
{
    __shared__ float t[64][65];
    const int k0 = blockIdx.x * 64;   // 8
    const int n0 = blockIdx.y * 64;   // 64
    const int g = n0 >> 10;
    const float* src = (g == 0) ? ms_W0 : (sp_W0 + (size_t)(g - 1) * 512 * 1024);
    const int col0 = n0 & 1023;
    const int tr = threadIdx.x >> 6, tc = threadIdx.x & 63;
#pragma unroll
    for (int i = 0; i < 16; ++i) {
        int k = tr + i * 4;
        t[k][tc] = src[(size_t)(k0 + k) * 1024 + col0 + tc];
    }
    __syncthreads();
    const int f = threadIdx.x >> 2;
    const int c4 = threadIdx.x & 3;
    ushort tmp[16];
#pragma unroll
    for (int j = 0; j < 16; ++j) tmp[j] = bf16_rn(t[c4 * 16 + j][f]);
    uint4* dst = (uint4*)(Wall + (size_t)(n0 + f) * 512 + k0 + c4 * 16);
    dst[0] = *(uint4*)&tmp[0];
    dst[1] = *(uint4*)&tmp[8];
}

// ---------------- H = emb @ [ms_W0 | W_src | W_ant] via MFMA (1024x512x3072)
__global__ __launch_bounds__(256) void gemm_h_mfma(
    const ushort* __restrict__ embb, const ushort* __restrict__ Wall,
    float* __restrict__ H)
{
    const int n0 = blockIdx.x * 128;  // 24
    const int m0 = blockIdx.y * 128;  // 8
    const int lane = threadIdx.x & 63, wave = threadIdx.x >> 6;
    const int wx = wave & 1, wy = wave >> 1;
    const int l15 = lane & 15, lq = lane >> 4;

    const ushort* arow[4];
#pragma unroll
    for (int mi = 0; mi < 4; ++mi)
        arow[mi] = embb + (size_t)(m0 + wy * 64 + mi * 16 + l15) * 512;
    const ushort* brow[4];
#pragma unroll
    for (int ni = 0; ni < 4; ++ni)
        brow[ni] = Wall + (size_t)(n0 + wx * 64 + ni * 16 + l15) * 512;

    f32x4 acc[4][4];
#pragma unroll
    for (int i = 0; i < 4; ++i)
#pragma unroll
        for (int j = 0; j < 4; ++j) acc[i][j] = (f32x4)0.f;

    for (int kt = 0; kt < 512; kt += 32) {
        const int ko = kt + lq * 8;
        bf16x8 av[4], bv[4];
#pragma unroll
        for (int mi = 0; mi < 4; ++mi) av[mi] = *(const bf16x8*)(arow[mi] + ko);
#pragma unroll
        for (int ni = 0; ni < 4; ++ni) bv[ni] = *(const bf16x8*)(brow[ni] + ko);
#pragma unroll
        for (int mi = 0; mi < 4; ++mi)
#pragma unroll
            for (int ni = 0; ni < 4; ++ni)
                acc[mi][ni] = __builtin_amdgcn_mfma_f32_16x16x32_bf16(av[mi], bv[ni], acc[mi][ni], 0, 0, 0);
    }
#pragma unroll
    for (int mi = 0; mi < 4; ++mi)
#pragma unroll
        for (int r = 0; r < 4; ++r) {
            int mrow = m0 + wy * 64 + mi * 16 + lq * 4 + r;
#pragma unroll
            for (int ni = 0; ni < 4; ++ni)
                H[(size_t)mrow * 3072 + n0 + wx * 64 + ni * 16 + l15] = acc[mi][ni][r];
        }
}

// ---------------- small projections
__global__ void small_proj(const float* __restrict__ speaker_emb,
                           const float* __restrict__ bucket_emb,
                           const float* __restrict__ sp_W0,
                           float* __restrict__ spk_proj, float* __restrict__ bkt_proj)
{
    int r = blockIdx.x; // 0..11
    const float* e; const float* W; float* out;
    if (r < 2) { e = speaker_emb + r * 20; W = sp_W0 + (size_t)1536 * 1024; out = spk_proj + r * 1024; }
    else       { e = bucket_emb + (r - 2) * 20; W = sp_W0 + (size_t)1556 * 1024; out = bkt_proj + (r - 2) * 1024; }
    float ek[20];
#pragma unroll
    for (int k = 0; k < 20; ++k) ek[k] = e[k];
    for (int f = threadIdx.x; f < 1024; f += blockDim.x) {
        float s = 0.f;
#pragma unroll
        for (int k = 0; k < 20; ++k) s = fmaf(ek[k], W[(size_t)k * 1024 + f], s);
        out[f] = s;
    }
}

// ---------------- mention scores
__global__ __launch_bounds__(256) void mention_score(
    const float* __restrict__ H, const float* __restrict__ ms_b0,
    const float* __restrict__ ms_W1, const float* __restrict__ ms_b1,
    float* __restrict__ ms)
{
    int m = blockIdx.x;
    float v = 0.f;
    for (int f = threadIdx.x; f < 1024; f += 256) {
        float h = H[(size_t)m * 3072 + f] + ms_b0[f];
        v += fmaxf(h, 0.f) * ms_W1[f];
    }
#pragma unroll
    for (int o = 1; o < 64; o <<= 1) v += __shfl_xor(v, o);
    __shared__ float sm[4];
    if ((threadIdx.x & 63) == 0) sm[threadIdx.x >> 6] = v;
    __syncthreads();
    if (threadIdx.x == 0) ms[m] = sm[0] + sm[1] + sm[2] + sm[3] + ms_b1[0];
}

// ---------------- pair scorer: block = one m, A staged once in LDS, 4 indep waves
__global__ __launch_bounds__(256, 1) void pair_mfma(
    const ushort* __restrict__ embb, const ushort* __restrict__ Wt,
    const float* __restrict__ H, const float* __restrict__ spk_proj,
    const float* __restrict__ bkt_proj, const float* __restrict__ sp_b0,
    const float* __restrict__ sp_W1, const int* __restrict__ speaker,
    float* __restrict__ slow)
{
    extern __shared__ ushort Alds[];                 // 128*LDSR ushorts
    float* red = (float*)(Alds + 128 * LDSR);        // 16*128 floats
    const int m = blockIdx.x;
    const int tid = threadIdx.x;

    // ---- build A[c][k] = bf16(em[k] * ea[k]) in LDS (once per block)
    {
        const int c = tid >> 1;
        const int kh = (tid & 1) * 256;
        int a = m - 1 - c; if (a < 0) a = 0;
        const ushort* ea = embb + (size_t)a * 512 + kh;
        const ushort* em = embb + (size_t)m * 512 + kh;
        ushort* dst = Alds + c * LDSR + kh;
        for (int j = 0; j < 256; j += 8) {
            bf16x8 va = *(const bf16x8*)(ea + j);
            bf16x8 vm = *(const bf16x8*)(em + j);
            uint pr[4];
#pragma unroll
            for (int p = 0; p < 4; ++p) {
                float q0 = bf16_to_f((ushort)va[2 * p])     * bf16_to_f((ushort)vm[2 * p]);
                float q1 = bf16_to_f((ushort)va[2 * p + 1]) * bf16_to_f((ushort)vm[2 * p + 1]);
                pr[p] = __builtin_amdgcn_perm(__float_as_uint(q1), __float_as_uint(q0), 0x07060302u);
            }
            *(bf16x8*)(dst + j) = *(bf16x8*)pr;
        }
    }
    __syncthreads();

    const int lane = tid & 63, wave = tid >> 6;
    const int l15 = lane & 15, lq = lane >> 4;
    const int spk_m = speaker[m];
    const ushort* aptr = Alds + l15 * LDSR + lq * 8;

    for (int pass = 0; pass < 4; ++pass) {
        const int cidx = pass * 4 + wave;
        const int f0 = cidx * 64;
        const ushort* brow[4];
#pragma unroll
        for (int ni = 0; ni < 4; ++ni) brow[ni] = Wt + (size_t)(f0 + ni * 16 + l15) * 512;

        f32x4 acc[8][4];
#pragma unroll
        for (int i = 0; i < 8; ++i)
#pragma unroll
            for (int j = 0; j < 4; ++j) acc[i][j] = (f32x4)0.f;

        // 2-stage register pipeline
        bf16x8 a_c[8], b_c[4], a_n[8], b_n[4];
#pragma unroll
        for (int mi = 0; mi < 8; ++mi) a_c[mi] = *(const bf16x8*)(aptr + mi * 16 * LDSR);
#pragma unroll
        for (int ni = 0; ni < 4; ++ni) b_c[ni] = *(const bf16x8*)(brow[ni]);

        for (int kt = 0; kt < 512; kt += 32) {
            const int kn = (kt + 32) & 511;   // last-iter wrap: loads valid, unused
#pragma unroll
            for (int mi = 0; mi < 8; ++mi) a_n[mi] = *(const bf16x8*)(aptr + mi * 16 * LDSR + kn);
#pragma unroll
            for (int ni = 0; ni < 4; ++ni) b_n[ni] = *(const bf16x8*)(brow[ni] + kn);
#pragma unroll
            for (int mi = 0; mi < 8; ++mi)
#pragma unroll
                for (int ni = 0; ni < 4; ++ni)
                    acc[mi][ni] = __builtin_amdgcn_mfma_f32_16x16x32_bf16(a_c[mi], b_c[ni], acc[mi][ni], 0, 0, 0);
#pragma unroll
            for (int mi = 0; mi < 8; ++mi) a_c[mi] = a_n[mi];
#pragma unroll
            for (int ni = 0; ni < 4; ++ni) b_c[ni] = b_n[ni];
        }

        // ---- epilogue for this 64-f chunk
        float srcb[4], w1v[4], sp0[4], sp1[4], bk9[4];
#pragma unroll
        for (int ni = 0; ni < 4; ++ni) {
            int fcol = f0 + ni * 16 + l15;
            srcb[ni] = H[(size_t)m * 3072 + 1024 + fcol] + sp_b0[fcol];
            w1v[ni]  = sp_W1[fcol];
            sp0[ni]  = spk_proj[fcol];
            sp1[ni]  = spk_proj[1024 + fcol];
            bk9[ni]  = bkt_proj[9 * 1024 + fcol];
        }
#pragma unroll
        for (int mi = 0; mi < 8; ++mi) {
#pragma unroll
            for (int r = 0; r < 4; ++r) {
                const int c = mi * 16 + lq * 4 + r;
                int a = m - 1 - c; if (a < 0) a = 0;
                const int ss = (speaker[a] == spk_m) ? 1 : 0;
                const int off = c + 1;
                int bk;
                if (off <= 4) bk = off;
                else { bk = 31 - __clz(off) + 3; if (bk > 9) bk = 9; }
                const float* antp = H + (size_t)a * 3072 + 2048;
                float s = 0.f;
#pragma unroll
                for (int ni = 0; ni < 4; ++ni) {
                    const int fcol = f0 + ni * 16 + l15;
                    float bval = (mi >= 4) ? bk9[ni] : bkt_proj[(size_t)bk * 1024 + fcol];
                    float spv  = ss ? sp1[ni] : sp0[ni];
                    float pre = acc[mi][ni][r] + srcb[ni] + antp[fcol] + spv + bval;
                    s += fmaxf(pre, 0.f) * w1v[ni];
                }
                s += __shfl_xor(s, 1); s += __shfl_xor(s, 2);
                s += __shfl_xor(s, 4); s += __shfl_xor(s, 8);
                if (l15 == 0) red[cidx * 128 + c] = s;
            }
        }
    }
    __syncthreads();
    if (tid < 128) {
        float s = 0.f;
#pragma unroll
        for (int i = 0; i < 16; ++i) s += red[i * 128 + tid];
        slow[(size_t)m * 128 + tid] = s;
    }
}

// ---------------- softmax + per-mention loss
__device__ __forceinline__ float bsum2(float v, float* sm) {
#pragma unroll
    for (int o = 1; o < 64; o <<= 1) v += __shfl_xor(v, o);
    __syncthreads();
    if ((threadIdx.x & 63) == 0) sm[threadIdx.x >> 6] = v;
    __syncthreads();
    return sm[0] + sm[1];
}
__device__ __forceinline__ float bmax2(float v, float* sm) {
#pragma unroll
    for (int o = 1; o < 64; o <<= 1) v = fmaxf(v, __shfl_xor(v, o));
    __syncthreads();
    if ((threadIdx.x & 63) == 0) sm[threadIdx.x >> 6] = v;
    __syncthreads();
    return fmaxf(sm[0], sm[1]);
}

__global__ __launch_bounds__(128) void softmax_loss(
    const float* __restrict__ slow, const float* __restrict__ ms,
    const float* __restrict__ sp_b1, const int* __restrict__ cluster,
    float* __restrict__ out, float* __restrict__ loss_partial)
{
    const int m = blockIdx.x, c = threadIdx.x;
    __shared__ float sm[2];
    const int raw = m - 1 - c;
    const bool maskv = raw >= 0;
    const int a = maskv ? raw : 0;
    float score = slow[(size_t)m * 128 + c] + sp_b1[0] + ms[m] + ms[a];
    if (!maskv) score = -INFINITY;

    float mx = fmaxf(bmax2(score, sm), 0.f);
    float e = expf(score - mx);
    float e0 = expf(0.f - mx);
    float sum = bsum2(e, sm) + e0;
    float p = e / sum, p0 = e0 / sum;
    const float eps = 1e-6f;
    p  = fminf(fmaxf(p,  eps), 1.f - eps);
    p0 = fminf(fmaxf(p0, eps), 1.f - eps);
    float sum2 = bsum2(p, sm) + p0;
    p /= sum2; p0 /= sum2;
    out[(size_t)m * 129 + 1 + c] = p;
    if (c == 0) out[(size_t)m * 129] = p0;

    const int cid = cluster[m];
    const bool lbl = maskv && (cid > 0) && (cluster[a] == cid);
    float anyc = bsum2(lbl ? 1.f : 0.f, sm);
    float lsum = bsum2(lbl ? -logf(p) : 0.f, sm);
    if (c == 0) {
        if (anyc == 0.f) lsum += -logf(p0);
        loss_partial[m] = lsum;
    }
}

__global__ void loss_sum(const float* __restrict__ lp, float* __restrict__ out) {
    float v = 0.f;
    for (int i = threadIdx.x; i < 1024; i += 256) v += lp[i];
#pragma unroll
    for (int o = 1; o < 64; o <<= 1) v += __shfl_xor(v, o);
    __shared__ float sm[4];
    if ((threadIdx.x & 63) == 0) sm[threadIdx.x >> 6] = v;
    __syncthreads();
    if (threadIdx.x == 0) out[(size_t)1024 * 129] = sm[0] + sm[1] + sm[2] + sm[3];
}

extern "C" void kernel_launch(void* const* d_in, const int* in_sizes, int n_in,
                              void* d_out, int out_size, void* d_ws, size_t ws_size,
                              hipStream_t stream)
{
    const float* emb   = (const float*)d_in[0];
    const int*   clus  = (const int*)  d_in[1];
    const int*   spk   = (const int*)  d_in[2];
    const float* ms_W0 = (const float*)d_in[3];
    const float* ms_b0 = (const float*)d_in[4];
    const float* ms_W1 = (const float*)d_in[5];
    const float* ms_b1 = (const float*)d_in[6];
    const float* sp_W0 = (const float*)d_in[7];
    const float* sp_b0 = (const float*)d_in[8];
    const float* sp_W1 = (const float*)d_in[9];
    const float* sp_b1 = (const float*)d_in[10];
    const float* spke  = (const float*)d_in[11];
    const float* bkte  = (const float*)d_in[12];

    float* ws = (float*)d_ws;
    float* H        = ws;
    float* slow     = ws + 3145728;
    float* spk_proj = ws + 3276800;
    float* bkt_proj = ws + 3278848;
    float* msc      = ws + 3289088;
    float* lossp    = ws + 3290112;
    ushort* embb    = (ushort*)(ws + 3291136);
    ushort* Wall    = (ushort*)(ws + 3553280);
    ushort* Wt      = Wall + (size_t)3072 * 512;
    float* out = (float*)d_out;

    static bool attr_set = false;
    if (!attr_set) {
        hipFuncSetAttribute((const void*)pair_mfma,
                            hipFuncAttributeMaxDynamicSharedMemorySize,
                            128 * LDSR * 2 + 16 * 128 * 4);
        attr_set = true;
    }

    hipLaunchKernelGGL(prep_emb, dim3(1024), dim3(256), 0, stream, emb, embb);
    hipLaunchKernelGGL(prep_wall, dim3(8, 64), dim3(256), 0, stream, ms_W0, sp_W0, Wall);
    hipLaunchKernelGGL(gemm_h_mfma, dim3(24, 8), dim3(256), 0, stream, embb, Wall, H);
    hipLaunchKernelGGL(small_proj, dim3(12), dim3(256), 0, stream, spke, bkte, sp_W0, spk_proj, bkt_proj);
    hipLaunchKernelGGL(mention_score, dim3(1024), dim3(256), 0, stream, H, ms_b0, ms_W1, ms_b1, msc);
    hipLaunchKernelGGL(pair_mfma, dim3(1024), dim3(256), 128 * LDSR * 2 + 16 * 128 * 4, stream,
                       embb, Wt, H, spk_proj, bkt_proj, sp_b0, sp_W1, spk, slow);
    hipLaunchKernelGGL(softmax_loss, dim3(1024), dim3(128), 0, stream,
                       slow, msc, sp_b1, clus, out, lossp);
    hipLaunchKernelGGL(loss_sum, dim3(1), dim3(256), 0, stream, lossp, out);
}

// Round 4
// 379.960 us; speedup vs baseline: 4.3645x; 1.1425x over previous
//
#include <hip/hip_runtime.h>
#include <math.h>

// Problem constants (B=1)
#define MM 1024
#define DD 512
#define CC 128
#define LDSR 520   // padded A row stride in ushorts

// ws layout (floats):
//  H[1024][3072]      @ 0        (0..1023 ms-hidden, 1024.. src_proj, 2048.. ant_proj)
//  slow[1024][128]    @ 3145728
//  spk_proj[2][1024]  @ 3276800
//  bkt_proj[10][1024] @ 3278848
//  ms[1024]           @ 3289088
//  lossp[1024]        @ 3290112
//  embb bf16[1024][512]  @ 3291136
//  Wall bf16[4096][512]  @ 3553280
//    rows: [0,1024)=ms_W0^T, [1024,2048)=W_src^T, [2048,3072)=W_ant^T, [3072,4096)=W_prod^T

typedef __attribute__((ext_vector_type(8))) short bf16x8;
typedef __attribute__((ext_vector_type(4))) float f32x4;

__device__ __forceinline__ ushort bf16_rn(float x) {
    uint u = __float_as_uint(x);
    uint r = u + 0x7fffu + ((u >> 16) & 1u);
    return (ushort)(r >> 16);
}
__device__ __forceinline__ float bf16_to_f(ushort u) {
    return __uint_as_float(((uint)u) << 16);
}

// ---------------- prep: emb fp32 -> bf16
__global__ __launch_bounds__(256) void prep_emb(const float* __restrict__ emb,
                                                ushort* __restrict__ embb)
{
    int i = blockIdx.x * 256 + threadIdx.x;
    float2 v = ((const float2*)emb)[i];
    ushort2 o;
    o.x = bf16_rn(v.x);
    o.y = bf16_rn(v.y);
    ((ushort2*)embb)[i] = o;
}

// ---------------- prep: transpose+convert all W0 blocks -> Wall[4096 n][512 k] bf16
__global__ __launch_bounds__(256) void prep_wall(const float* __restrict__ ms_W0,
                                                 const float* __restrict__ sp_W0,
                                                 ushort* __restrict__ Wall)
{
    __shared__ float t[64][65];
    const int k0 = blockIdx.x * 64;   // 8
    const int n0 = blockIdx.y * 64;   // 64
    const int g = n0 >> 10;
    const float* src = (g == 0) ? ms_W0 : (sp_W0 + (size_t)(g - 1) * 512 * 1024);
    const int col0 = n0 & 1023;
    const int tr = threadIdx.x >> 6, tc = threadIdx.x & 63;
#pragma unroll
    for (int i = 0; i < 16; ++i) {
        int k = tr + i * 4;
        t[k][tc] = src[(size_t)(k0 + k) * 1024 + col0 + tc];
    }
    __syncthreads();
    const int f = threadIdx.x >> 2;
    const int c4 = threadIdx.x & 3;
    ushort tmp[16];
#pragma unroll
    for (int j = 0; j < 16; ++j) tmp[j] = bf16_rn(t[c4 * 16 + j][f]);
    uint4* dst = (uint4*)(Wall + (size_t)(n0 + f) * 512 + k0 + c4 * 16);
    dst[0] = *(uint4*)&tmp[0];
    dst[1] = *(uint4*)&tmp[8];
}

// ---------------- H = emb @ [ms_W0 | W_src | W_ant] via MFMA (1024x512x3072)
__global__ __launch_bounds__(256) void gemm_h_mfma(
    const ushort* __restrict__ embb, const ushort* __restrict__ Wall,
    float* __restrict__ H)
{
    const int n0 = blockIdx.x * 128;  // 24
    const int m0 = blockIdx.y * 128;  // 8
    const int lane = threadIdx.x & 63, wave = threadIdx.x >> 6;
    const int wx = wave & 1, wy = wave >> 1;
    const int l15 = lane & 15, lq = lane >> 4;

    const ushort* arow[4];
#pragma unroll
    for (int mi = 0; mi < 4; ++mi)
        arow[mi] = embb + (size_t)(m0 + wy * 64 + mi * 16 + l15) * 512;
    const ushort* brow[4];
#pragma unroll
    for (int ni = 0; ni < 4; ++ni)
        brow[ni] = Wall + (size_t)(n0 + wx * 64 + ni * 16 + l15) * 512;

    f32x4 acc[4][4];
#pragma unroll
    for (int i = 0; i < 4; ++i)
#pragma unroll
        for (int j = 0; j < 4; ++j) acc[i][j] = (f32x4)0.f;

    for (int kt = 0; kt < 512; kt += 32) {
        const int ko = kt + lq * 8;
        bf16x8 av[4], bv[4];
#pragma unroll
        for (int mi = 0; mi < 4; ++mi) av[mi] = *(const bf16x8*)(arow[mi] + ko);
#pragma unroll
        for (int ni = 0; ni < 4; ++ni) bv[ni] = *(const bf16x8*)(brow[ni] + ko);
#pragma unroll
        for (int mi = 0; mi < 4; ++mi)
#pragma unroll
            for (int ni = 0; ni < 4; ++ni)
                acc[mi][ni] = __builtin_amdgcn_mfma_f32_16x16x32_bf16(av[mi], bv[ni], acc[mi][ni], 0, 0, 0);
    }
#pragma unroll
    for (int mi = 0; mi < 4; ++mi)
#pragma unroll
        for (int r = 0; r < 4; ++r) {
            int mrow = m0 + wy * 64 + mi * 16 + lq * 4 + r;
#pragma unroll
            for (int ni = 0; ni < 4; ++ni)
                H[(size_t)mrow * 3072 + n0 + wx * 64 + ni * 16 + l15] = acc[mi][ni][r];
        }
}

// ---------------- small projections
__global__ void small_proj(const float* __restrict__ speaker_emb,
                           const float* __restrict__ bucket_emb,
                           const float* __restrict__ sp_W0,
                           float* __restrict__ spk_proj, float* __restrict__ bkt_proj)
{
    int r = blockIdx.x; // 0..11
    const float* e; const float* W; float* out;
    if (r < 2) { e = speaker_emb + r * 20; W = sp_W0 + (size_t)1536 * 1024; out = spk_proj + r * 1024; }
    else       { e = bucket_emb + (r - 2) * 20; W = sp_W0 + (size_t)1556 * 1024; out = bkt_proj + (r - 2) * 1024; }
    float ek[20];
#pragma unroll
    for (int k = 0; k < 20; ++k) ek[k] = e[k];
    for (int f = threadIdx.x; f < 1024; f += blockDim.x) {
        float s = 0.f;
#pragma unroll
        for (int k = 0; k < 20; ++k) s = fmaf(ek[k], W[(size_t)k * 1024 + f], s);
        out[f] = s;
    }
}

// ---------------- mention scores
__global__ __launch_bounds__(256) void mention_score(
    const float* __restrict__ H, const float* __restrict__ ms_b0,
    const float* __restrict__ ms_W1, const float* __restrict__ ms_b1,
    float* __restrict__ ms)
{
    int m = blockIdx.x;
    float v = 0.f;
    for (int f = threadIdx.x; f < 1024; f += 256) {
        float h = H[(size_t)m * 3072 + f] + ms_b0[f];
        v += fmaxf(h, 0.f) * ms_W1[f];
    }
#pragma unroll
    for (int o = 1; o < 64; o <<= 1) v += __shfl_xor(v, o);
    __shared__ float sm[4];
    if ((threadIdx.x & 63) == 0) sm[threadIdx.x >> 6] = v;
    __syncthreads();
    if (threadIdx.x == 0) ms[m] = sm[0] + sm[1] + sm[2] + sm[3] + ms_b1[0];
}

// ---------------- pair scorer: block = one m; A in LDS; 8 waves (2/SIMD), 2 f-chunks each
__global__ __launch_bounds__(512, 2) void pair_mfma(
    const ushort* __restrict__ embb, const ushort* __restrict__ Wt,
    const float* __restrict__ H, const float* __restrict__ spk_proj,
    const float* __restrict__ bkt_proj, const float* __restrict__ sp_b0,
    const float* __restrict__ sp_W1, const int* __restrict__ speaker,
    float* __restrict__ slow)
{
    extern __shared__ ushort Alds[];                 // 128*LDSR ushorts
    float* red = (float*)(Alds + 128 * LDSR);        // 16*128 floats
    const int m = blockIdx.x;
    const int tid = threadIdx.x;

    // ---- build A[c][k] = bf16(em[k] * ea[k]) in LDS (once per block; 512 threads)
    {
        const int c = tid >> 2;                      // 0..127
        const int kh = (tid & 3) * 128;              // 4 k-quarters
        int a = m - 1 - c; if (a < 0) a = 0;
        const ushort* ea = embb + (size_t)a * 512 + kh;
        const ushort* em = embb + (size_t)m * 512 + kh;
        ushort* dst = Alds + c * LDSR + kh;
        for (int j = 0; j < 128; j += 8) {
            bf16x8 va = *(const bf16x8*)(ea + j);
            bf16x8 vm = *(const bf16x8*)(em + j);
            uint pr[4];
#pragma unroll
            for (int p = 0; p < 4; ++p) {
                float q0 = bf16_to_f((ushort)va[2 * p])     * bf16_to_f((ushort)vm[2 * p]);
                float q1 = bf16_to_f((ushort)va[2 * p + 1]) * bf16_to_f((ushort)vm[2 * p + 1]);
                pr[p] = __builtin_amdgcn_perm(__float_as_uint(q1), __float_as_uint(q0), 0x07060302u);
            }
            *(bf16x8*)(dst + j) = *(bf16x8*)pr;
        }
    }
    __syncthreads();

    const int lane = tid & 63, wave = tid >> 6;      // 8 waves
    const int l15 = lane & 15, lq = lane >> 4;
    const int spk_m = speaker[m];
    const ushort* aptr = Alds + l15 * LDSR + lq * 8;

    for (int pass = 0; pass < 2; ++pass) {
        const int cidx = pass * 8 + wave;            // 0..15 f-chunk
        const int f0 = cidx * 64;
        const ushort* brow[4];
#pragma unroll
        for (int ni = 0; ni < 4; ++ni) brow[ni] = Wt + (size_t)(f0 + ni * 16 + l15) * 512;

        f32x4 acc[8][4];
#pragma unroll
        for (int i = 0; i < 8; ++i)
#pragma unroll
            for (int j = 0; j < 4; ++j) acc[i][j] = (f32x4)0.f;

        // 2-stage register pipeline
        bf16x8 a_c[8], b_c[4], a_n[8], b_n[4];
#pragma unroll
        for (int mi = 0; mi < 8; ++mi) a_c[mi] = *(const bf16x8*)(aptr + mi * 16 * LDSR);
#pragma unroll
        for (int ni = 0; ni < 4; ++ni) b_c[ni] = *(const bf16x8*)(brow[ni]);

        for (int kt = 0; kt < 512; kt += 32) {
            const int kn = (kt + 32) & 511;   // last-iter wrap: loads valid, unused
#pragma unroll
            for (int mi = 0; mi < 8; ++mi) a_n[mi] = *(const bf16x8*)(aptr + mi * 16 * LDSR + kn);
#pragma unroll
            for (int ni = 0; ni < 4; ++ni) b_n[ni] = *(const bf16x8*)(brow[ni] + kn);
#pragma unroll
            for (int mi = 0; mi < 8; ++mi)
#pragma unroll
                for (int ni = 0; ni < 4; ++ni)
                    acc[mi][ni] = __builtin_amdgcn_mfma_f32_16x16x32_bf16(a_c[mi], b_c[ni], acc[mi][ni], 0, 0, 0);
#pragma unroll
            for (int mi = 0; mi < 8; ++mi) a_c[mi] = a_n[mi];
#pragma unroll
            for (int ni = 0; ni < 4; ++ni) b_c[ni] = b_n[ni];
        }

        // ---- epilogue for this 64-f chunk
        float srcb[4], w1v[4], sp0[4], sp1[4], bk9[4];
#pragma unroll
        for (int ni = 0; ni < 4; ++ni) {
            int fcol = f0 + ni * 16 + l15;
            srcb[ni] = H[(size_t)m * 3072 + 1024 + fcol] + sp_b0[fcol];
            w1v[ni]  = sp_W1[fcol];
            sp0[ni]  = spk_proj[fcol];
            sp1[ni]  = spk_proj[1024 + fcol];
            bk9[ni]  = bkt_proj[9 * 1024 + fcol];
        }
#pragma unroll
        for (int mi = 0; mi < 8; ++mi) {
#pragma unroll
            for (int r = 0; r < 4; ++r) {
                const int c = mi * 16 + lq * 4 + r;
                int a = m - 1 - c; if (a < 0) a = 0;
                const int ss = (speaker[a] == spk_m) ? 1 : 0;
                const int off = c + 1;
                int bk;
                if (off <= 4) bk = off;
                else { bk = 31 - __clz(off) + 3; if (bk > 9) bk = 9; }
                const float* antp = H + (size_t)a * 3072 + 2048;
                float s = 0.f;
#pragma unroll
                for (int ni = 0; ni < 4; ++ni) {
                    const int fcol = f0 + ni * 16 + l15;
                    float bval = (mi >= 4) ? bk9[ni] : bkt_proj[(size_t)bk * 1024 + fcol];
                    float spv  = ss ? sp1[ni] : sp0[ni];
                    float pre = acc[mi][ni][r] + srcb[ni] + antp[fcol] + spv + bval;
                    s += fmaxf(pre, 0.f) * w1v[ni];
                }
                s += __shfl_xor(s, 1); s += __shfl_xor(s, 2);
                s += __shfl_xor(s, 4); s += __shfl_xor(s, 8);
                if (l15 == 0) red[cidx * 128 + c] = s;
            }
        }
    }
    __syncthreads();
    if (tid < 128) {
        float s = 0.f;
#pragma unroll
        for (int i = 0; i < 16; ++i) s += red[i * 128 + tid];
        slow[(size_t)m * 128 + tid] = s;
    }
}

// ---------------- softmax + per-mention loss
__device__ __forceinline__ float bsum2(float v, float* sm) {
#pragma unroll
    for (int o = 1; o < 64; o <<= 1) v += __shfl_xor(v, o);
    __syncthreads();
    if ((threadIdx.x & 63) == 0) sm[threadIdx.x >> 6] = v;
    __syncthreads();
    return sm[0] + sm[1];
}
__device__ __forceinline__ float bmax2(float v, float* sm) {
#pragma unroll
    for (int o = 1; o < 64; o <<= 1) v = fmaxf(v, __shfl_xor(v, o));
    __syncthreads();
    if ((threadIdx.x & 63) == 0) sm[threadIdx.x >> 6] = v;
    __syncthreads();
    return fmaxf(sm[0], sm[1]);
}

__global__ __launch_bounds__(128) void softmax_loss(
    const float* __restrict__ slow, const float* __restrict__ ms,
    const float* __restrict__ sp_b1, const int* __restrict__ cluster,
    float* __restrict__ out, float* __restrict__ loss_partial)
{
    const int m = blockIdx.x, c = threadIdx.x;
    __shared__ float sm[2];
    const int raw = m - 1 - c;
    const bool maskv = raw >= 0;
    const int a = maskv ? raw : 0;
    float score = slow[(size_t)m * 128 + c] + sp_b1[0] + ms[m] + ms[a];
    if (!maskv) score = -INFINITY;

    float mx = fmaxf(bmax2(score, sm), 0.f);
    float e = expf(score - mx);
    float e0 = expf(0.f - mx);
    float sum = bsum2(e, sm) + e0;
    float p = e / sum, p0 = e0 / sum;
    const float eps = 1e-6f;
    p  = fminf(fmaxf(p,  eps), 1.f - eps);
    p0 = fminf(fmaxf(p0, eps), 1.f - eps);
    float sum2 = bsum2(p, sm) + p0;
    p /= sum2; p0 /= sum2;
    out[(size_t)m * 129 + 1 + c] = p;
    if (c == 0) out[(size_t)m * 129] = p0;

    const int cid = cluster[m];
    const bool lbl = maskv && (cid > 0) && (cluster[a] == cid);
    float anyc = bsum2(lbl ? 1.f : 0.f, sm);
    float lsum = bsum2(lbl ? -logf(p) : 0.f, sm);
    if (c == 0) {
        if (anyc == 0.f) lsum += -logf(p0);
        loss_partial[m] = lsum;
    }
}

__global__ void loss_sum(const float* __restrict__ lp, float* __restrict__ out) {
    float v = 0.f;
    for (int i = threadIdx.x; i < 1024; i += 256) v += lp[i];
#pragma unroll
    for (int o = 1; o < 64; o <<= 1) v += __shfl_xor(v, o);
    __shared__ float sm[4];
    if ((threadIdx.x & 63) == 0) sm[threadIdx.x >> 6] = v;
    __syncthreads();
    if (threadIdx.x == 0) out[(size_t)1024 * 129] = sm[0] + sm[1] + sm[2] + sm[3];
}

extern "C" void kernel_launch(void* const* d_in, const int* in_sizes, int n_in,
                              void* d_out, int out_size, void* d_ws, size_t ws_size,
                              hipStream_t stream)
{
    const float* emb   = (const float*)d_in[0];
    const int*   clus  = (const int*)  d_in[1];
    const int*   spk   = (const int*)  d_in[2];
    const float* ms_W0 = (const float*)d_in[3];
    const float* ms_b0 = (const float*)d_in[4];
    const float* ms_W1 = (const float*)d_in[5];
    const float* ms_b1 = (const float*)d_in[6];
    const float* sp_W0 = (const float*)d_in[7];
    const float* sp_b0 = (const float*)d_in[8];
    const float* sp_W1 = (const float*)d_in[9];
    const float* sp_b1 = (const float*)d_in[10];
    const float* spke  = (const float*)d_in[11];
    const float* bkte  = (const float*)d_in[12];

    float* ws = (float*)d_ws;
    float* H        = ws;
    float* slow     = ws + 3145728;
    float* spk_proj = ws + 3276800;
    float* bkt_proj = ws + 3278848;
    float* msc      = ws + 3289088;
    float* lossp    = ws + 3290112;
    ushort* embb    = (ushort*)(ws + 3291136);
    ushort* Wall    = (ushort*)(ws + 3553280);
    ushort* Wt      = Wall + (size_t)3072 * 512;
    float* out = (float*)d_out;

    static bool attr_set = false;
    if (!attr_set) {
        hipFuncSetAttribute((const void*)pair_mfma,
                            hipFuncAttributeMaxDynamicSharedMemorySize,
                            128 * LDSR * 2 + 16 * 128 * 4);
        attr_set = true;
    }

    hipLaunchKernelGGL(prep_emb, dim3(1024), dim3(256), 0, stream, emb, embb);
    hipLaunchKernelGGL(prep_wall, dim3(8, 64), dim3(256), 0, stream, ms_W0, sp_W0, Wall);
    hipLaunchKernelGGL(gemm_h_mfma, dim3(24, 8), dim3(256), 0, stream, embb, Wall, H);
    hipLaunchKernelGGL(small_proj, dim3(12), dim3(256), 0, stream, spke, bkte, sp_W0, spk_proj, bkt_proj);
    hipLaunchKernelGGL(mention_score, dim3(1024), dim3(256), 0, stream, H, ms_b0, ms_W1, ms_b1, msc);
    hipLaunchKernelGGL(pair_mfma, dim3(1024), dim3(512), 128 * LDSR * 2 + 16 * 128 * 4, stream,
                       embb, Wt, H, spk_proj, bkt_proj, sp_b0, sp_W1, spk, slow);
    hipLaunchKernelGGL(softmax_loss, dim3(1024), dim3(128), 0, stream,
                       slow, msc, sp_b1, clus, out, lossp);
    hipLaunchKernelGGL(loss_sum, dim3(1), dim3(256), 0, stream, lossp, out);
}